// Round 1
// baseline (293.666 us; speedup 1.0000x reference)
//
#include <hip/hip_runtime.h>
#include <stdint.h>
#include <stddef.h>

typedef __attribute__((ext_vector_type(8))) short short8;
typedef __attribute__((ext_vector_type(4))) float f32x4;
typedef __attribute__((ext_vector_type(4))) unsigned short us4;

#define DEVI static __device__ __forceinline__

DEVI unsigned short f2bf(float f) {
  unsigned u = __builtin_bit_cast(unsigned, f);
  u += 0x7FFFu + ((u >> 16) & 1u);
  return (unsigned short)(u >> 16);
}

DEVI f32x4 mfma16(short8 a, short8 b, f32x4 c) {
  return __builtin_amdgcn_mfma_f32_16x16x32_bf16(a, b, c, 0, 0, 0);
}

// ---------------- convert x (fp32 -> bf16) ----------------
__global__ __launch_bounds__(256) void k_cvt_x(const float* __restrict__ x,
                                               unsigned short* __restrict__ xb) {
  size_t i = ((size_t)blockIdx.x * 256 + threadIdx.x) * 8;
  f32x4 a = *(const f32x4*)(x + i);
  f32x4 b = *(const f32x4*)(x + i + 4);
  short8 v;
#pragma unroll
  for (int j = 0; j < 4; ++j) {
    v[j] = (short)f2bf(a[j]);
    v[4 + j] = (short)f2bf(b[j]);
  }
  *(short8*)(xb + i) = v;
}

// ---------------- transpose + convert W (K x N fp32 -> N x K bf16) ----------------
__global__ __launch_bounds__(256) void k_twT(const float* __restrict__ W,
                                             unsigned short* __restrict__ WT) {
  __shared__ float tile[64][65];
  const int n0 = blockIdx.x * 64, k0 = blockIdx.y * 64;
  const int t = threadIdx.x, rr = t >> 4, cc = (t & 15) * 4;
#pragma unroll
  for (int i = 0; i < 4; ++i) {
    int row = i * 16 + rr;
    f32x4 v = *(const f32x4*)(W + (size_t)(k0 + row) * 1024 + n0 + cc);
#pragma unroll
    for (int j = 0; j < 4; ++j) tile[row][cc + j] = v[j];
  }
  __syncthreads();
#pragma unroll
  for (int i = 0; i < 4; ++i) {
    int nrow = i * 16 + rr;
    us4 u;
#pragma unroll
    for (int j = 0; j < 4; ++j) u[j] = f2bf(tile[cc + j][nrow]);
    *(us4*)(WT + (size_t)(n0 + nrow) * 1024 + k0 + cc) = u;
  }
}

// ---------------- GEMM core: C(128x128) = A(Mx1024) @ Bt(Nx1024)^T ----------------
DEVI void gemm_core(const unsigned short* __restrict__ A,
                    const unsigned short* __restrict__ Bt,
                    int mt, int nt, char* lds, f32x4 (&acc)[4][4]) {
  const int t = threadIdx.x;
  const int l = t & 63, c = l & 15, g = l >> 4;
  const int w = t >> 6, wr = w >> 1, wc = w & 1;
  const int srow = t >> 3, scol = (t & 7) * 8;
  for (int k0 = 0; k0 < 1024; k0 += 64) {
    short8 ar[4], br[4];
#pragma unroll
    for (int it = 0; it < 4; ++it) {
      int row = it * 32 + srow;
      ar[it] = *(const short8*)(A + (size_t)(mt * 128 + row) * 1024 + k0 + scol);
      br[it] = *(const short8*)(Bt + (size_t)(nt * 128 + row) * 1024 + k0 + scol);
    }
    __syncthreads();
#pragma unroll
    for (int it = 0; it < 4; ++it) {
      int row = it * 32 + srow;
      int off = (row * 128 + scol * 2) ^ ((row & 7) << 4);
      *(short8*)(lds + off) = ar[it];
      *(short8*)(lds + 16384 + off) = br[it];
    }
    __syncthreads();
#pragma unroll
    for (int ks = 0; ks < 2; ++ks) {
      short8 af[4], bfr[4];
#pragma unroll
      for (int m = 0; m < 4; ++m) {
        int row = wr * 64 + m * 16 + c;
        af[m] = *(const short8*)(lds + ((row * 128 + ks * 64 + 16 * g) ^ ((row & 7) << 4)));
      }
#pragma unroll
      for (int n = 0; n < 4; ++n) {
        int row = wc * 64 + n * 16 + c;
        bfr[n] = *(const short8*)(lds + 16384 + ((row * 128 + ks * 64 + 16 * g) ^ ((row & 7) << 4)));
      }
#pragma unroll
      for (int m = 0; m < 4; ++m)
#pragma unroll
        for (int n = 0; n < 4; ++n) acc[m][n] = mfma16(af[m], bfr[n], acc[m][n]);
    }
  }
}

// ---------------- QKV GEMM with scatter epilogue to (B,H,T,Dh) ----------------
__global__ __launch_bounds__(256) void k_gemm_qkv(
    const unsigned short* __restrict__ A,
    const unsigned short* __restrict__ W0, const unsigned short* __restrict__ W1,
    const unsigned short* __restrict__ W2,
    const float* __restrict__ b0, const float* __restrict__ b1, const float* __restrict__ b2,
    unsigned short* __restrict__ O0, unsigned short* __restrict__ O1,
    unsigned short* __restrict__ O2) {
  __shared__ char lds[32768];
  const int z = blockIdx.z;
  const unsigned short* Bt = (z == 0) ? W0 : (z == 1) ? W1 : W2;
  const float* bias = (z == 0) ? b0 : (z == 1) ? b1 : b2;
  unsigned short* out = (z == 0) ? O0 : (z == 1) ? O1 : O2;
  f32x4 acc[4][4];
#pragma unroll
  for (int m = 0; m < 4; ++m)
#pragma unroll
    for (int n = 0; n < 4; ++n) acc[m][n] = (f32x4){0.f, 0.f, 0.f, 0.f};
  const int mt = blockIdx.y, nt = blockIdx.x;
  gemm_core(A, Bt, mt, nt, lds, acc);
  const int t = threadIdx.x, l = t & 63, c = l & 15, g = l >> 4;
  const int w = t >> 6, wr = w >> 1, wc = w & 1;
#pragma unroll
  for (int n = 0; n < 4; ++n) {
    int colg = nt * 128 + wc * 64 + n * 16 + c;
    float bv = bias[colg];
    int h = colg >> 6, d = colg & 63;
#pragma unroll
    for (int m = 0; m < 4; ++m)
#pragma unroll
      for (int r = 0; r < 4; ++r) {
        int rowg = mt * 128 + wr * 64 + m * 16 + 4 * g + r;
        int b = rowg >> 11, tt = rowg & 2047;
        out[((size_t)(b * 16 + h) * 2048 + tt) * 64 + d] = f2bf(acc[m][n][r] + bv);
      }
  }
}

// ---------------- projection GEMM, fp32 epilogue ----------------
__global__ __launch_bounds__(256) void k_gemm_proj(const unsigned short* __restrict__ A,
                                                   const unsigned short* __restrict__ Bt,
                                                   const float* __restrict__ bias,
                                                   float* __restrict__ Y) {
  __shared__ char lds[32768];
  f32x4 acc[4][4];
#pragma unroll
  for (int m = 0; m < 4; ++m)
#pragma unroll
    for (int n = 0; n < 4; ++n) acc[m][n] = (f32x4){0.f, 0.f, 0.f, 0.f};
  const int mt = blockIdx.y, nt = blockIdx.x;
  gemm_core(A, Bt, mt, nt, lds, acc);
  const int t = threadIdx.x, l = t & 63, c = l & 15, g = l >> 4;
  const int w = t >> 6, wr = w >> 1, wc = w & 1;
#pragma unroll
  for (int n = 0; n < 4; ++n) {
    int colg = nt * 128 + wc * 64 + n * 16 + c;
    float bv = bias[colg];
#pragma unroll
    for (int m = 0; m < 4; ++m)
#pragma unroll
      for (int r = 0; r < 4; ++r) {
        int rowg = mt * 128 + wr * 64 + m * 16 + 4 * g + r;
        Y[(size_t)rowg * 1024 + colg] = acc[m][n][r] + bv;
      }
  }
}

// ---------------- flash attention: 128 Q rows/block, 64-row KV tiles ----------------
__global__ __launch_bounds__(256) void k_attn(const unsigned short* __restrict__ Q,
                                              const unsigned short* __restrict__ K,
                                              const unsigned short* __restrict__ V,
                                              unsigned short* __restrict__ O) {
  __shared__ char lds[32768];  // K tile 8KB | Vt tile 8KB | P per-wave 4x4KB
  const int qt = blockIdx.x, bh = blockIdx.y;
  const int t = threadIdx.x, w = t >> 6, l = t & 63, c = l & 15, g = l >> 4;
  const size_t base = (size_t)bh * 2048 * 64;
  short8 qf[2][2];
#pragma unroll
  for (int fq = 0; fq < 2; ++fq)
#pragma unroll
    for (int ks = 0; ks < 2; ++ks)
      qf[fq][ks] = *(const short8*)(Q + base +
                                    (size_t)(qt * 128 + w * 32 + fq * 16 + c) * 64 + ks * 32 + 8 * g);
  f32x4 o[2][4];
  float m_s[2][4], l_s[2][4];
#pragma unroll
  for (int fq = 0; fq < 2; ++fq) {
#pragma unroll
    for (int fd = 0; fd < 4; ++fd) o[fq][fd] = (f32x4){0.f, 0.f, 0.f, 0.f};
#pragma unroll
    for (int r = 0; r < 4; ++r) {
      m_s[fq][r] = -1e30f;
      l_s[fq][r] = 0.f;
    }
  }
  const int srow = t >> 3, scb = (t & 7) * 8;
  const int ktmax = qt * 2 + 1;
  for (int kt = 0; kt <= ktmax; ++kt) {
    const unsigned short* Kg = K + base + (size_t)kt * 64 * 64;
    const unsigned short* Vg = V + base + (size_t)kt * 64 * 64;
    short8 kr[2], vr[2];
#pragma unroll
    for (int it = 0; it < 2; ++it) {
      int row = it * 32 + srow;
      kr[it] = *(const short8*)(Kg + row * 64 + scb);
      vr[it] = *(const short8*)(Vg + row * 64 + scb);
    }
    __syncthreads();  // previous tile fully consumed
#pragma unroll
    for (int it = 0; it < 2; ++it) {
      int row = it * 32 + srow;
      *(short8*)(lds + ((row * 128 + scb * 2) ^ ((row & 7) << 4))) = kr[it];
#pragma unroll
      for (int j = 0; j < 8; ++j) {
        int dd = scb + j;  // store V transposed: Vt[d][kv]
        *(unsigned short*)(lds + 8192 +
                           ((dd * 128 + row * 2) ^ ((((dd >> 3) ^ dd) & 7) << 4))) =
            (unsigned short)vr[it][j];
      }
    }
    __syncthreads();
    // S = Q K^T  (per wave: 32 q-rows x 64 kv)
    f32x4 s[2][4];
#pragma unroll
    for (int fk = 0; fk < 4; ++fk) {
      int krow = fk * 16 + c;
      int kx = (krow & 7) << 4;
      short8 kf0 = *(const short8*)(lds + ((krow * 128 + 16 * g) ^ kx));
      short8 kf1 = *(const short8*)(lds + ((krow * 128 + 64 + 16 * g) ^ kx));
#pragma unroll
      for (int fq = 0; fq < 2; ++fq) {
        f32x4 a = (f32x4){0.f, 0.f, 0.f, 0.f};
        a = mfma16(qf[fq][0], kf0, a);
        a = mfma16(qf[fq][1], kf1, a);
        s[fq][fk] = a;
      }
    }
    // online softmax, write P (bf16) to per-wave LDS
#pragma unroll
    for (int fq = 0; fq < 2; ++fq) {
#pragma unroll
      for (int r = 0; r < 4; ++r) {
        int qg = qt * 128 + w * 32 + fq * 16 + g * 4 + r;
        float mx = -1e30f;
#pragma unroll
        for (int fk = 0; fk < 4; ++fk) {
          float sv = s[fq][fk][r] * 0.125f;
          if (kt * 64 + fk * 16 + c > qg) sv = -1e30f;
          s[fq][fk][r] = sv;
          mx = fmaxf(mx, sv);
        }
#pragma unroll
        for (int dd = 1; dd < 16; dd <<= 1) mx = fmaxf(mx, __shfl_xor(mx, dd, 64));
        float mold = m_s[fq][r];
        float mnew = fmaxf(mold, mx);
        float corr = __expf(mold - mnew);
        float psum = 0.f;
        int prow = fq * 16 + g * 4 + r;
        int px = (prow & 7) << 4;
#pragma unroll
        for (int fk = 0; fk < 4; ++fk) {
          float p = __expf(s[fq][fk][r] - mnew);
          psum += p;
          *(unsigned short*)(lds + 16384 + w * 4096 +
                             ((prow * 128 + (fk * 16 + c) * 2) ^ px)) = f2bf(p);
        }
#pragma unroll
        for (int dd = 1; dd < 16; dd <<= 1) psum += __shfl_xor(psum, dd, 64);
        m_s[fq][r] = mnew;
        l_s[fq][r] = l_s[fq][r] * corr + psum;
#pragma unroll
        for (int fd = 0; fd < 4; ++fd) o[fq][fd][r] *= corr;
      }
    }
    // O += P @ V
#pragma unroll
    for (int ks2 = 0; ks2 < 2; ++ks2) {
      short8 pf[2];
#pragma unroll
      for (int fq = 0; fq < 2; ++fq) {
        int prow = fq * 16 + c;
        pf[fq] = *(const short8*)(lds + 16384 + w * 4096 +
                                  ((prow * 128 + ks2 * 64 + 16 * g) ^ ((prow & 7) << 4)));
      }
#pragma unroll
      for (int fd = 0; fd < 4; ++fd) {
        int vrow = fd * 16 + c;
        short8 vf = *(const short8*)(lds + 8192 +
                                     ((vrow * 128 + ks2 * 64 + 16 * g) ^
                                      ((((vrow >> 3) ^ vrow) & 7) << 4)));
#pragma unroll
        for (int fq = 0; fq < 2; ++fq) o[fq][fd] = mfma16(pf[fq], vf, o[fq][fd]);
      }
    }
  }
  // normalize and store O as (B,T,1024) bf16
  const int b = bh >> 4, h = bh & 15;
#pragma unroll
  for (int fq = 0; fq < 2; ++fq)
#pragma unroll
    for (int fd = 0; fd < 4; ++fd)
#pragma unroll
      for (int r = 0; r < 4; ++r) {
        int qrow = qt * 128 + w * 32 + fq * 16 + g * 4 + r;
        float val = o[fq][fd][r] / l_s[fq][r];
        O[((size_t)b * 2048 + qrow) * 1024 + h * 64 + fd * 16 + c] = f2bf(val);
      }
}

// ---------------- LayerNorm over last dim (1024), fp32 ----------------
__global__ __launch_bounds__(256) void k_ln(const float* __restrict__ Y,
                                            const float* __restrict__ gamma,
                                            const float* __restrict__ beta,
                                            float* __restrict__ out) {
  __shared__ float red[8];
  const int row = blockIdx.x, t = threadIdx.x, w = t >> 6, l = t & 63;
  const float* yr = Y + (size_t)row * 1024;
  f32x4 v = *(const f32x4*)(yr + t * 4);
  float s = v[0] + v[1] + v[2] + v[3];
  float ss = v[0] * v[0] + v[1] * v[1] + v[2] * v[2] + v[3] * v[3];
#pragma unroll
  for (int d = 1; d < 64; d <<= 1) {
    s += __shfl_xor(s, d, 64);
    ss += __shfl_xor(ss, d, 64);
  }
  if (l == 0) {
    red[w] = s;
    red[4 + w] = ss;
  }
  __syncthreads();
  s = red[0] + red[1] + red[2] + red[3];
  ss = red[4] + red[5] + red[6] + red[7];
  float mean = s * (1.f / 1024.f);
  float var = ss * (1.f / 1024.f) - mean * mean;
  float rstd = rsqrtf(var + 1e-5f);
  f32x4 gv = *(const f32x4*)(gamma + t * 4);
  f32x4 bv = *(const f32x4*)(beta + t * 4);
  f32x4 ov;
#pragma unroll
  for (int j = 0; j < 4; ++j) ov[j] = (v[j] - mean) * rstd * gv[j] + bv[j];
  *(f32x4*)(out + (size_t)row * 1024 + t * 4) = ov;
}

extern "C" void kernel_launch(void* const* d_in, const int* in_sizes, int n_in,
                              void* d_out, int out_size, void* d_ws, size_t ws_size,
                              hipStream_t stream) {
  (void)in_sizes; (void)n_in; (void)out_size; (void)ws_size;
  const float* x = (const float*)d_in[0];
  const float* Wq = (const float*)d_in[1];
  const float* bq = (const float*)d_in[2];
  const float* Wk = (const float*)d_in[3];
  const float* bk = (const float*)d_in[4];
  const float* Wv = (const float*)d_in[5];
  const float* bv = (const float*)d_in[6];
  const float* Wo = (const float*)d_in[7];
  const float* bo = (const float*)d_in[8];
  const float* gamma = (const float*)d_in[9];
  const float* beta = (const float*)d_in[10];
  char* ws = (char*)d_ws;
  const size_t MB = 1024 * 1024;
  unsigned short* xb = (unsigned short*)(ws);            // 8 MB
  unsigned short* WqT = (unsigned short*)(ws + 8 * MB);  // 2 MB
  unsigned short* WkT = (unsigned short*)(ws + 10 * MB);
  unsigned short* WvT = (unsigned short*)(ws + 12 * MB);
  unsigned short* WoT = (unsigned short*)(ws + 14 * MB);
  unsigned short* Qb = (unsigned short*)(ws + 16 * MB);  // 8 MB each
  unsigned short* Kb = (unsigned short*)(ws + 24 * MB);
  unsigned short* Vb = (unsigned short*)(ws + 32 * MB);
  unsigned short* Ob = (unsigned short*)(ws + 40 * MB);
  float* Y = (float*)(ws + 16 * MB);  // 16 MB, overlaps Qb/Kb (dead after attention)

  k_cvt_x<<<2048, 256, 0, stream>>>(x, xb);
  k_twT<<<dim3(16, 16), 256, 0, stream>>>(Wq, WqT);
  k_twT<<<dim3(16, 16), 256, 0, stream>>>(Wk, WkT);
  k_twT<<<dim3(16, 16), 256, 0, stream>>>(Wv, WvT);
  k_twT<<<dim3(16, 16), 256, 0, stream>>>(Wo, WoT);
  k_gemm_qkv<<<dim3(8, 32, 3), 256, 0, stream>>>(xb, WqT, WkT, WvT, bq, bk, bv, Qb, Kb, Vb);
  k_attn<<<dim3(16, 32), 256, 0, stream>>>(Qb, Kb, Vb, Ob);
  k_gemm_proj<<<dim3(8, 32), 256, 0, stream>>>(Ob, WoT, bo, Y);
  k_ln<<<4096, 256, 0, stream>>>(Y, gamma, beta, (float*)d_out);
}

// Round 2
// 164.157 us; speedup vs baseline: 1.7889x; 1.7889x over previous
//
#include <hip/hip_runtime.h>
#include <stdint.h>
#include <stddef.h>

typedef __attribute__((ext_vector_type(8))) short short8;
typedef __attribute__((ext_vector_type(4))) float f32x4;
typedef __attribute__((ext_vector_type(16))) float f32x16;
typedef __attribute__((ext_vector_type(4))) unsigned short us4;
typedef __attribute__((ext_vector_type(4))) unsigned u32x4;

#define DEVI static __device__ __forceinline__

DEVI unsigned short f2bf(float f) {
  unsigned u = __builtin_bit_cast(unsigned, f);
  u += 0x7FFFu + ((u >> 16) & 1u);
  return (unsigned short)(u >> 16);
}

DEVI f32x4 mfma16(short8 a, short8 b, f32x4 c) {
  return __builtin_amdgcn_mfma_f32_16x16x32_bf16(a, b, c, 0, 0, 0);
}

DEVI f32x16 mfma32(short8 a, short8 b, f32x16 c) {
  return __builtin_amdgcn_mfma_f32_32x32x16_bf16(a, b, c, 0, 0, 0);
}

DEVI unsigned cvtpk(float lo, float hi) {
  unsigned r;
  asm("v_cvt_pk_bf16_f32 %0, %1, %2" : "=v"(r) : "v"(lo), "v"(hi));
  return r;
}

// v_permlane32_swap_b32: a.hi <-> b.lo  => a' = {a.lo, b.lo}, b' = {a.hi, b.hi}
DEVI void plswap(unsigned& a, unsigned& b) {
  asm("v_permlane32_swap_b32 %0, %1" : "+v"(a), "+v"(b));
}

DEVI f32x16 zero16() {
  f32x16 z;
#pragma unroll
  for (int i = 0; i < 16; ++i) z[i] = 0.f;
  return z;
}

// ---------------- convert x (fp32 -> bf16) ----------------
__global__ __launch_bounds__(256) void k_cvt_x(const float* __restrict__ x,
                                               unsigned short* __restrict__ xb) {
  size_t i = ((size_t)blockIdx.x * 256 + threadIdx.x) * 8;
  f32x4 a = *(const f32x4*)(x + i);
  f32x4 b = *(const f32x4*)(x + i + 4);
  short8 v;
#pragma unroll
  for (int j = 0; j < 4; ++j) {
    v[j] = (short)f2bf(a[j]);
    v[4 + j] = (short)f2bf(b[j]);
  }
  *(short8*)(xb + i) = v;
}

// ---------------- transpose + convert W (K x N fp32 -> N x K bf16) ----------------
__global__ __launch_bounds__(256) void k_twT(const float* __restrict__ W,
                                             unsigned short* __restrict__ WT) {
  __shared__ float tile[64][65];
  const int n0 = blockIdx.x * 64, k0 = blockIdx.y * 64;
  const int t = threadIdx.x, rr = t >> 4, cc = (t & 15) * 4;
#pragma unroll
  for (int i = 0; i < 4; ++i) {
    int row = i * 16 + rr;
    f32x4 v = *(const f32x4*)(W + (size_t)(k0 + row) * 1024 + n0 + cc);
#pragma unroll
    for (int j = 0; j < 4; ++j) tile[row][cc + j] = v[j];
  }
  __syncthreads();
#pragma unroll
  for (int i = 0; i < 4; ++i) {
    int nrow = i * 16 + rr;
    us4 u;
#pragma unroll
    for (int j = 0; j < 4; ++j) u[j] = f2bf(tile[cc + j][nrow]);
    *(us4*)(WT + (size_t)(n0 + nrow) * 1024 + k0 + cc) = u;
  }
}

// ---------------- GEMM core: C(128x128) = A(Mx1024) @ Bt(Nx1024)^T ----------------
DEVI void gemm_core(const unsigned short* __restrict__ A,
                    const unsigned short* __restrict__ Bt,
                    int mt, int nt, char* lds, f32x4 (&acc)[4][4]) {
  const int t = threadIdx.x;
  const int l = t & 63, c = l & 15, g = l >> 4;
  const int w = t >> 6, wr = w >> 1, wc = w & 1;
  const int srow = t >> 3, scol = (t & 7) * 8;
  for (int k0 = 0; k0 < 1024; k0 += 64) {
    short8 ar[4], br[4];
#pragma unroll
    for (int it = 0; it < 4; ++it) {
      int row = it * 32 + srow;
      ar[it] = *(const short8*)(A + (size_t)(mt * 128 + row) * 1024 + k0 + scol);
      br[it] = *(const short8*)(Bt + (size_t)(nt * 128 + row) * 1024 + k0 + scol);
    }
    __syncthreads();
#pragma unroll
    for (int it = 0; it < 4; ++it) {
      int row = it * 32 + srow;
      int off = (row * 128 + scol * 2) ^ ((row & 7) << 4);
      *(short8*)(lds + off) = ar[it];
      *(short8*)(lds + 16384 + off) = br[it];
    }
    __syncthreads();
#pragma unroll
    for (int ks = 0; ks < 2; ++ks) {
      short8 af[4], bfr[4];
#pragma unroll
      for (int m = 0; m < 4; ++m) {
        int row = wr * 64 + m * 16 + c;
        af[m] = *(const short8*)(lds + ((row * 128 + ks * 64 + 16 * g) ^ ((row & 7) << 4)));
      }
#pragma unroll
      for (int n = 0; n < 4; ++n) {
        int row = wc * 64 + n * 16 + c;
        bfr[n] = *(const short8*)(lds + 16384 + ((row * 128 + ks * 64 + 16 * g) ^ ((row & 7) << 4)));
      }
#pragma unroll
      for (int m = 0; m < 4; ++m)
#pragma unroll
        for (int n = 0; n < 4; ++n) acc[m][n] = mfma16(af[m], bfr[n], acc[m][n]);
    }
  }
}

// ---------------- QKV GEMM; Q pre-scaled by 0.125; V stored transposed ----------------
__global__ __launch_bounds__(256) void k_gemm_qkv(
    const unsigned short* __restrict__ A,
    const unsigned short* __restrict__ W0, const unsigned short* __restrict__ W1,
    const unsigned short* __restrict__ W2,
    const float* __restrict__ b0, const float* __restrict__ b1, const float* __restrict__ b2,
    unsigned short* __restrict__ O0, unsigned short* __restrict__ O1,
    unsigned short* __restrict__ O2) {
  __shared__ char lds[32768];
  const int z = blockIdx.z;
  const unsigned short* Bt = (z == 0) ? W0 : (z == 1) ? W1 : W2;
  const float* bias = (z == 0) ? b0 : (z == 1) ? b1 : b2;
  unsigned short* out = (z == 0) ? O0 : (z == 1) ? O1 : O2;
  f32x4 acc[4][4];
#pragma unroll
  for (int m = 0; m < 4; ++m)
#pragma unroll
    for (int n = 0; n < 4; ++n) acc[m][n] = (f32x4){0.f, 0.f, 0.f, 0.f};
  const int mt = blockIdx.y, nt = blockIdx.x;
  gemm_core(A, Bt, mt, nt, lds, acc);
  const int t = threadIdx.x, l = t & 63, c = l & 15, g = l >> 4;
  const int w = t >> 6, wr = w >> 1, wc = w & 1;
  if (z == 2) {
    // V^T layout: VT[((b*16+h)*64 + d) * 2048 + tt]
#pragma unroll
    for (int n = 0; n < 4; ++n) {
      int colg = nt * 128 + wc * 64 + n * 16 + c;
      float bvv = bias[colg];
      int h = colg >> 6, d = colg & 63;
#pragma unroll
      for (int m = 0; m < 4; ++m)
#pragma unroll
        for (int r = 0; r < 4; ++r) {
          int rowg = mt * 128 + wr * 64 + m * 16 + 4 * g + r;
          int b = rowg >> 11, tt = rowg & 2047;
          out[((size_t)(b * 16 + h) * 64 + d) * 2048 + tt] = f2bf(acc[m][n][r] + bvv);
        }
    }
  } else {
    const float sc = (z == 0) ? 0.125f : 1.0f;  // fold 1/sqrt(Dh) into Q
#pragma unroll
    for (int n = 0; n < 4; ++n) {
      int colg = nt * 128 + wc * 64 + n * 16 + c;
      float bvv = bias[colg];
      int h = colg >> 6, d = colg & 63;
#pragma unroll
      for (int m = 0; m < 4; ++m)
#pragma unroll
        for (int r = 0; r < 4; ++r) {
          int rowg = mt * 128 + wr * 64 + m * 16 + 4 * g + r;
          int b = rowg >> 11, tt = rowg & 2047;
          out[((size_t)(b * 16 + h) * 2048 + tt) * 64 + d] = f2bf((acc[m][n][r] + bvv) * sc);
        }
    }
  }
}

// ---------------- projection GEMM, fp32 epilogue ----------------
__global__ __launch_bounds__(256) void k_gemm_proj(const unsigned short* __restrict__ A,
                                                   const unsigned short* __restrict__ Bt,
                                                   const float* __restrict__ bias,
                                                   float* __restrict__ Y) {
  __shared__ char lds[32768];
  f32x4 acc[4][4];
#pragma unroll
  for (int m = 0; m < 4; ++m)
#pragma unroll
    for (int n = 0; n < 4; ++n) acc[m][n] = (f32x4){0.f, 0.f, 0.f, 0.f};
  const int mt = blockIdx.y, nt = blockIdx.x;
  gemm_core(A, Bt, mt, nt, lds, acc);
  const int t = threadIdx.x, l = t & 63, c = l & 15, g = l >> 4;
  const int w = t >> 6, wr = w >> 1, wc = w & 1;
#pragma unroll
  for (int n = 0; n < 4; ++n) {
    int colg = nt * 128 + wc * 64 + n * 16 + c;
    float bv = bias[colg];
#pragma unroll
    for (int m = 0; m < 4; ++m)
#pragma unroll
      for (int r = 0; r < 4; ++r) {
        int rowg = mt * 128 + wr * 64 + m * 16 + 4 * g + r;
        Y[(size_t)rowg * 1024 + colg] = acc[m][n][r] + bv;
      }
  }
}

// ---------------- flash attention v2: swapped QK^T, 32x32 MFMA, no LDS ----------------
// Per wave: 32 q rows. Block = 4 waves = 128 q rows. Grid remapped long-first so
// block j and j+256 (qt = 15-a and a) pair to constant work per CU.
__global__ __launch_bounds__(256) void k_attn2(const unsigned short* __restrict__ Q,
                                               const unsigned short* __restrict__ K,
                                               const unsigned short* __restrict__ VT,
                                               unsigned short* __restrict__ O) {
  const int bid = blockIdx.x;
  const int half = bid >> 8, j = bid & 255;
  const int qt = half ? (j >> 5) : (15 - (j >> 5));
  const int bh = j & 31;
  const int w = threadIdx.x >> 6, l = threadIdx.x & 63;
  const int lq = l & 31, hi = l >> 5;
  const int q0 = qt * 128 + w * 32;
  const unsigned short* Kb = K + (size_t)bh * 2048 * 64 + 8 * hi;
  const unsigned short* Vb = VT + (size_t)bh * 64 * 2048 + (size_t)lq * 2048 + 8 * hi;
  // Q fragments (pre-scaled by 0.125 at GEMM epilogue)
  short8 qf[4];
#pragma unroll
  for (int ds = 0; ds < 4; ++ds)
    qf[ds] = *(const short8*)(K - K + Q + (size_t)bh * 2048 * 64 + (size_t)(q0 + lq) * 64 +
                              16 * ds + 8 * hi);
  f32x16 oacc[2];
  oacc[0] = zero16();
  oacc[1] = zero16();
  float m_s = -1e30f, l_s = 0.f;
  const int ntiles = (q0 >> 6) + 1;
  for (int kt = 0; kt < ntiles; ++kt) {
    const int kv0 = kt * 64;
    // K fragments (direct global; rows = kv, k-dim = d)
    short8 kf0[4], kf1[4];
#pragma unroll
    for (int ds = 0; ds < 4; ++ds) {
      kf0[ds] = *(const short8*)(Kb + (size_t)(kv0 + lq) * 64 + 16 * ds);
      kf1[ds] = *(const short8*)(Kb + (size_t)(kv0 + 32 + lq) * 64 + 16 * ds);
    }
    // S^T = K · Q^T : lane holds S[k][q=lq], k = 32*f + (r&3)+8*(r>>2)+4*hi
    f32x16 st0 = zero16(), st1 = zero16();
#pragma unroll
    for (int ds = 0; ds < 4; ++ds) {
      st0 = mfma32(kf0[ds], qf[ds], st0);
      st1 = mfma32(kf1[ds], qf[ds], st1);
    }
    // V^T fragments (issue early so latency hides under softmax)
    short8 vf[2][4];
#pragma unroll
    for (int fd = 0; fd < 2; ++fd)
#pragma unroll
      for (int s = 0; s < 4; ++s)
        vf[fd][s] = *(const short8*)(Vb + (size_t)(fd * 32) * 2048 + kv0 + 16 * s);
    // causal mask (last tile only; wave-uniform branch)
    if (kt == ntiles - 1) {
      const int qg = q0 + lq;
#pragma unroll
      for (int r = 0; r < 16; ++r) {
        int kr = kv0 + (r & 3) + 8 * (r >> 2) + 4 * hi;
        if (kr > qg) st0[r] = -1e30f;
        if (kr + 32 > qg) st1[r] = -1e30f;
      }
    }
    // row max: in-lane over 32 + one cross-half exchange
    float mx = fmaxf(st0[0], st1[0]);
#pragma unroll
    for (int r = 1; r < 16; ++r) mx = fmaxf(mx, fmaxf(st0[r], st1[r]));
    mx = fmaxf(mx, __shfl_xor(mx, 32, 64));
    // online-softmax update with defer-max (T13, THR=8)
    if (!__all(mx - m_s <= 8.f)) {
      float mnew = fmaxf(m_s, mx);
      float corr = __expf(m_s - mnew);
      m_s = mnew;
      l_s *= corr;
#pragma unroll
      for (int r = 0; r < 16; ++r) {
        oacc[0][r] *= corr;
        oacc[1][r] *= corr;
      }
    }
    // p = exp(s - m), pack to bf16 words
    unsigned Wp[2][4][2];
    float psum = 0.f;
#pragma unroll
    for (int f = 0; f < 2; ++f)
#pragma unroll
      for (int m4 = 0; m4 < 4; ++m4) {
        float p0 = __expf((f ? st1 : st0)[4 * m4 + 0] - m_s);
        float p1 = __expf((f ? st1 : st0)[4 * m4 + 1] - m_s);
        float p2 = __expf((f ? st1 : st0)[4 * m4 + 2] - m_s);
        float p3 = __expf((f ? st1 : st0)[4 * m4 + 3] - m_s);
        psum += (p0 + p1) + (p2 + p3);
        Wp[f][m4][0] = cvtpk(p0, p1);
        Wp[f][m4][1] = cvtpk(p2, p3);
      }
    psum += __shfl_xor(psum, 32, 64);
    l_s += psum;
    // O^T += V^T · P^T : per k-step s build P fragment via permlane32_swap
#pragma unroll
    for (int s = 0; s < 4; ++s) {
      const int f = s >> 1, s2 = s & 1;
      unsigned a0 = Wp[f][2 * s2][0], b0 = Wp[f][2 * s2 + 1][0];
      unsigned a1 = Wp[f][2 * s2][1], b1 = Wp[f][2 * s2 + 1][1];
      plswap(a0, b0);
      plswap(a1, b1);
      u32x4 pw = {a0, a1, b0, b1};
      short8 pf = __builtin_bit_cast(short8, pw);
      oacc[0] = mfma32(vf[0][s], pf, oacc[0]);
      oacc[1] = mfma32(vf[1][s], pf, oacc[1]);
    }
  }
  // epilogue: lane owns q = lq; d lives in regs. Store (B,T,1024) bf16.
  const float inv = 1.0f / l_s;
  const int b = bh >> 4, h = bh & 15;
  unsigned short* orow = O + ((size_t)b * 2048 + q0 + lq) * 1024 + h * 64 + 4 * hi;
#pragma unroll
  for (int f = 0; f < 2; ++f)
#pragma unroll
    for (int m4 = 0; m4 < 4; ++m4) {
      us4 u;
#pragma unroll
      for (int rr = 0; rr < 4; ++rr) u[rr] = f2bf(oacc[f][4 * m4 + rr] * inv);
      *(us4*)(orow + f * 32 + m4 * 8) = u;
    }
}

// ---------------- LayerNorm over last dim (1024), fp32 ----------------
__global__ __launch_bounds__(256) void k_ln(const float* __restrict__ Y,
                                            const float* __restrict__ gamma,
                                            const float* __restrict__ beta,
                                            float* __restrict__ out) {
  __shared__ float red[8];
  const int row = blockIdx.x, t = threadIdx.x, w = t >> 6, l = t & 63;
  const float* yr = Y + (size_t)row * 1024;
  f32x4 v = *(const f32x4*)(yr + t * 4);
  float s = v[0] + v[1] + v[2] + v[3];
  float ss = v[0] * v[0] + v[1] * v[1] + v[2] * v[2] + v[3] * v[3];
#pragma unroll
  for (int d = 1; d < 64; d <<= 1) {
    s += __shfl_xor(s, d, 64);
    ss += __shfl_xor(ss, d, 64);
  }
  if (l == 0) {
    red[w] = s;
    red[4 + w] = ss;
  }
  __syncthreads();
  s = red[0] + red[1] + red[2] + red[3];
  ss = red[4] + red[5] + red[6] + red[7];
  float mean = s * (1.f / 1024.f);
  float var = ss * (1.f / 1024.f) - mean * mean;
  float rstd = rsqrtf(var + 1e-5f);
  f32x4 gv = *(const f32x4*)(gamma + t * 4);
  f32x4 bv = *(const f32x4*)(beta + t * 4);
  f32x4 ov;
#pragma unroll
  for (int j = 0; j < 4; ++j) ov[j] = (v[j] - mean) * rstd * gv[j] + bv[j];
  *(f32x4*)(out + (size_t)row * 1024 + t * 4) = ov;
}

extern "C" void kernel_launch(void* const* d_in, const int* in_sizes, int n_in,
                              void* d_out, int out_size, void* d_ws, size_t ws_size,
                              hipStream_t stream) {
  (void)in_sizes; (void)n_in; (void)out_size; (void)ws_size;
  const float* x = (const float*)d_in[0];
  const float* Wq = (const float*)d_in[1];
  const float* bq = (const float*)d_in[2];
  const float* Wk = (const float*)d_in[3];
  const float* bk = (const float*)d_in[4];
  const float* Wv = (const float*)d_in[5];
  const float* bv = (const float*)d_in[6];
  const float* Wo = (const float*)d_in[7];
  const float* bo = (const float*)d_in[8];
  const float* gamma = (const float*)d_in[9];
  const float* beta = (const float*)d_in[10];
  char* ws = (char*)d_ws;
  const size_t MB = 1024 * 1024;
  unsigned short* xb = (unsigned short*)(ws);            // 8 MB
  unsigned short* WqT = (unsigned short*)(ws + 8 * MB);  // 2 MB each
  unsigned short* WkT = (unsigned short*)(ws + 10 * MB);
  unsigned short* WvT = (unsigned short*)(ws + 12 * MB);
  unsigned short* WoT = (unsigned short*)(ws + 14 * MB);
  unsigned short* Qb = (unsigned short*)(ws + 16 * MB);   // 8 MB each
  unsigned short* Kb = (unsigned short*)(ws + 24 * MB);
  unsigned short* VTb = (unsigned short*)(ws + 32 * MB);  // V transposed (BH,64,2048)
  unsigned short* Ob = (unsigned short*)(ws + 40 * MB);
  float* Y = (float*)(ws + 16 * MB);  // 16 MB, overlaps Qb/Kb (dead after attention)

  k_cvt_x<<<2048, 256, 0, stream>>>(x, xb);
  k_twT<<<dim3(16, 16), 256, 0, stream>>>(Wq, WqT);
  k_twT<<<dim3(16, 16), 256, 0, stream>>>(Wk, WkT);
  k_twT<<<dim3(16, 16), 256, 0, stream>>>(Wv, WvT);
  k_twT<<<dim3(16, 16), 256, 0, stream>>>(Wo, WoT);
  k_gemm_qkv<<<dim3(8, 32, 3), 256, 0, stream>>>(xb, WqT, WkT, WvT, bq, bk, bv, Qb, Kb, VTb);
  k_attn2<<<512, 256, 0, stream>>>(Qb, Kb, VTb, Ob);
  k_gemm_proj<<<dim3(8, 32), 256, 0, stream>>>(Ob, WoT, bo, Y);
  k_ln<<<4096, 256, 0, stream>>>(Y, gamma, beta, (float*)d_out);
}